// Round 1
// baseline (19241.521 us; speedup 1.0000x reference)
//
#include <hip/hip_runtime.h>
#include <hip/hip_fp16.h>

// LSTM: B=32, T=1024, IN=256, H=256, L=2, bidirectional.
// ws layout: xg f16 [2][32][1024][1024] = 134,217,728 B ; WT f32 [4][256][1024] = 4,194,304 B
// total ws needed = 138,412,032 B

#define T_LEN 1024
#define BATCH 32
#define HID   256
#define G4    1024   // 4*HID

struct __align__(8) Half4 { __half x, y, z, w; };

__device__ __forceinline__ float sigm(float x) { return 1.0f / (1.0f + __expf(-x)); }

// ---- transpose W_hh [1024,256] -> WT [256,1024]; z selects one of 4 matrices ----
__global__ void wt_kernel(const float* __restrict__ w0, const float* __restrict__ w1,
                          const float* __restrict__ w2, const float* __restrict__ w3,
                          float* __restrict__ wt)
{
    const float* w = (blockIdx.z == 0) ? w0 : (blockIdx.z == 1) ? w1
                   : (blockIdx.z == 2) ? w2 : w3;
    float* o = wt + (size_t)blockIdx.z * (HID * G4);
    int idx = blockIdx.x * 256 + threadIdx.x;   // 0 .. 262143
    int n = idx & (G4 - 1);
    int k = idx >> 10;
    o[(size_t)k * G4 + n] = w[(size_t)n * HID + k];
}

// ---- projection: xg[dir][m][n] = sum_k A[m][k]*W[n][k] + bih[n] + bhh[n], stored f16 ----
// A:[32768,K] f32, W:[1024,K] f32. 128x128 tile, BK=32, 256 threads, 8x8 microtile.
__global__ __launch_bounds__(256) void proj_kernel(
    const float* __restrict__ A, int K,
    const float* __restrict__ Wf, const float* __restrict__ Wr,
    const float* __restrict__ bih_f, const float* __restrict__ bhh_f,
    const float* __restrict__ bih_r, const float* __restrict__ bhh_r,
    __half* __restrict__ xg)
{
    const int dir = blockIdx.z;
    const float* __restrict__ W   = dir ? Wr    : Wf;
    const float* __restrict__ bih = dir ? bih_r : bih_f;
    const float* __restrict__ bhh = dir ? bhh_r : bhh_f;
    __half* __restrict__ outp = xg + (size_t)dir * ((size_t)BATCH * T_LEN * G4);

    __shared__ float As[32][132];   // [k][m], stride 132 (16B-aligned rows, conflict-light)
    __shared__ float Bs[32][132];   // [k][n]

    const int tid = threadIdx.x;
    const int tx  = tid & 15;
    const int ty  = tid >> 4;
    const int tx4 = tx * 4;
    const int ty4 = ty * 4;
    const int m0  = blockIdx.y * 128;
    const int n0  = blockIdx.x * 128;

    float acc[8][8];
    #pragma unroll
    for (int i = 0; i < 8; ++i)
        #pragma unroll
        for (int j = 0; j < 8; ++j) acc[i][j] = 0.f;

    for (int k0 = 0; k0 < K; k0 += 32) {
        #pragma unroll
        for (int it = 0; it < 4; ++it) {
            int f   = tid + it * 256;       // 0..1023 float4 slots
            int row = f >> 3;               // 0..127
            int c4  = (f & 7) * 4;          // 0,4,..,28
            float4 av = *reinterpret_cast<const float4*>(&A[(size_t)(m0 + row) * K + k0 + c4]);
            float4 bv = *reinterpret_cast<const float4*>(&W[(size_t)(n0 + row) * K + k0 + c4]);
            As[c4 + 0][row] = av.x; As[c4 + 1][row] = av.y;
            As[c4 + 2][row] = av.z; As[c4 + 3][row] = av.w;
            Bs[c4 + 0][row] = bv.x; Bs[c4 + 1][row] = bv.y;
            Bs[c4 + 2][row] = bv.z; Bs[c4 + 3][row] = bv.w;
        }
        __syncthreads();
        #pragma unroll
        for (int k = 0; k < 32; ++k) {
            float4 a0 = *reinterpret_cast<const float4*>(&As[k][ty4]);
            float4 a1 = *reinterpret_cast<const float4*>(&As[k][64 + ty4]);
            float4 b0 = *reinterpret_cast<const float4*>(&Bs[k][tx4]);
            float4 b1 = *reinterpret_cast<const float4*>(&Bs[k][64 + tx4]);
            float a[8] = {a0.x,a0.y,a0.z,a0.w,a1.x,a1.y,a1.z,a1.w};
            float b[8] = {b0.x,b0.y,b0.z,b0.w,b1.x,b1.y,b1.z,b1.w};
            #pragma unroll
            for (int i = 0; i < 8; ++i)
                #pragma unroll
                for (int j = 0; j < 8; ++j)
                    acc[i][j] = fmaf(a[i], b[j], acc[i][j]);
        }
        __syncthreads();
    }

    float bb[8];
    #pragma unroll
    for (int j = 0; j < 8; ++j) {
        int n = n0 + ((j < 4) ? (tx4 + j) : (64 + tx4 + (j - 4)));
        bb[j] = bih[n] + bhh[n];
    }
    #pragma unroll
    for (int i = 0; i < 8; ++i) {
        int m = m0 + ((i < 4) ? (ty4 + i) : (64 + ty4 + (i - 4)));
        Half4 v0, v1;
        v0.x = __float2half(acc[i][0] + bb[0]);
        v0.y = __float2half(acc[i][1] + bb[1]);
        v0.z = __float2half(acc[i][2] + bb[2]);
        v0.w = __float2half(acc[i][3] + bb[3]);
        v1.x = __float2half(acc[i][4] + bb[4]);
        v1.y = __float2half(acc[i][5] + bb[5]);
        v1.z = __float2half(acc[i][6] + bb[6]);
        v1.w = __float2half(acc[i][7] + bb[7]);
        *reinterpret_cast<Half4*>(&outp[(size_t)m * G4 + n0 + tx4])      = v0;
        *reinterpret_cast<Half4*>(&outp[(size_t)m * G4 + n0 + 64 + tx4]) = v1;
    }
}

// ---- recurrence: one workgroup per (batch, direction); no inter-wg sync ----
// xg: f16 [2][32][1024][1024]; wt: f32 [2][256][1024] (this layer); outp: [32][1024][512]
__global__ __launch_bounds__(256) void recur_kernel(
    const __half* __restrict__ xg,
    const float*  __restrict__ wt,
    float*        __restrict__ outp)
{
    const int dir = blockIdx.x & 1;
    const int b   = blockIdx.x >> 1;
    const __half* __restrict__ xgp = xg + ((size_t)dir * BATCH + b) * ((size_t)T_LEN * G4);
    const float*  __restrict__ W   = wt + (size_t)dir * (HID * G4);

    __shared__ float h_lds[HID];
    __shared__ float g_lds[G4];

    const int tid = threadIdx.x;
    const int n4  = tid * 4;                 // this thread's 4 gate columns
    const float* __restrict__ Wp = W + n4;

    h_lds[tid] = 0.f;
    float c = 0.f;
    __syncthreads();

    for (int s = 0; s < T_LEN; ++s) {
        const int t = dir ? (T_LEN - 1 - s) : s;

        // gates[n4..n4+3] = xg[b,t,n4..] + sum_k h[k] * WT[k][n4..]
        const __half* xr = xgp + (size_t)t * G4 + n4;
        float4 acc, acc2;
        {
            __half2 xa = *reinterpret_cast<const __half2*>(xr);
            __half2 xb = *reinterpret_cast<const __half2*>(xr + 2);
            float2 fa = __half22float2(xa), fb = __half22float2(xb);
            acc.x = fa.x; acc.y = fa.y; acc.z = fb.x; acc.w = fb.y;
        }
        acc2.x = acc2.y = acc2.z = acc2.w = 0.f;

        #pragma unroll 8
        for (int k = 0; k < HID; k += 2) {
            float h0 = h_lds[k], h1 = h_lds[k + 1];
            float4 w0 = *reinterpret_cast<const float4*>(&Wp[(size_t)k * G4]);
            float4 w1 = *reinterpret_cast<const float4*>(&Wp[(size_t)(k + 1) * G4]);
            acc.x  = fmaf(h0, w0.x, acc.x);   acc.y  = fmaf(h0, w0.y, acc.y);
            acc.z  = fmaf(h0, w0.z, acc.z);   acc.w  = fmaf(h0, w0.w, acc.w);
            acc2.x = fmaf(h1, w1.x, acc2.x);  acc2.y = fmaf(h1, w1.y, acc2.y);
            acc2.z = fmaf(h1, w1.z, acc2.z);  acc2.w = fmaf(h1, w1.w, acc2.w);
        }
        acc.x += acc2.x; acc.y += acc2.y; acc.z += acc2.z; acc.w += acc2.w;
        *reinterpret_cast<float4*>(&g_lds[n4]) = acc;
        __syncthreads();

        // each thread owns h-index tid: gates i,f,g,o at tid, 256+tid, 512+tid, 768+tid
        float gi = g_lds[tid];
        float gf = g_lds[HID + tid];
        float gg = g_lds[2 * HID + tid];
        float go = g_lds[3 * HID + tid];
        c = sigm(gf) * c + sigm(gi) * tanhf(gg);
        float h = sigm(go) * tanhf(c);
        h_lds[tid] = h;
        outp[((size_t)b * T_LEN + t) * (2 * HID) + dir * HID + tid] = h;
        __syncthreads();
    }
}

extern "C" void kernel_launch(void* const* d_in, const int* in_sizes, int n_in,
                              void* d_out, int out_size, void* d_ws, size_t ws_size,
                              hipStream_t stream)
{
    const float* x       = (const float*)d_in[0];
    const float* W_ih_f0 = (const float*)d_in[1];
    const float* W_hh_f0 = (const float*)d_in[2];
    const float* b_ih_f0 = (const float*)d_in[3];
    const float* b_hh_f0 = (const float*)d_in[4];
    const float* W_ih_r0 = (const float*)d_in[5];
    const float* W_hh_r0 = (const float*)d_in[6];
    const float* b_ih_r0 = (const float*)d_in[7];
    const float* b_hh_r0 = (const float*)d_in[8];
    const float* W_ih_f1 = (const float*)d_in[9];
    const float* W_hh_f1 = (const float*)d_in[10];
    const float* b_ih_f1 = (const float*)d_in[11];
    const float* b_hh_f1 = (const float*)d_in[12];
    const float* W_ih_r1 = (const float*)d_in[13];
    const float* W_hh_r1 = (const float*)d_in[14];
    const float* b_ih_r1 = (const float*)d_in[15];
    const float* b_hh_r1 = (const float*)d_in[16];

    float* outp = (float*)d_out;

    __half* xg = (__half*)d_ws;
    const size_t xg_elems = (size_t)2 * BATCH * T_LEN * G4;          // 67,108,864
    float* wt = (float*)((char*)d_ws + xg_elems * sizeof(__half));   // 4 matrices f32

    // pre-transpose all 4 W_hh -> [256][1024]   (order: f0, r0, f1, r1)
    wt_kernel<<<dim3(1024, 1, 4), 256, 0, stream>>>(W_hh_f0, W_hh_r0, W_hh_f1, W_hh_r1, wt);

    // ---- layer 0 ----
    proj_kernel<<<dim3(8, 256, 2), 256, 0, stream>>>(x, 256, W_ih_f0, W_ih_r0,
        b_ih_f0, b_hh_f0, b_ih_r0, b_hh_r0, xg);
    recur_kernel<<<dim3(64), 256, 0, stream>>>(xg, wt, outp);        // d_out = concat scratch

    // ---- layer 1 ----  (proj reads d_out fully before recur overwrites it; stream-ordered)
    proj_kernel<<<dim3(8, 256, 2), 256, 0, stream>>>(outp, 512, W_ih_f1, W_ih_r1,
        b_ih_f1, b_hh_f1, b_ih_r1, b_hh_r1, xg);
    recur_kernel<<<dim3(64), 256, 0, stream>>>(xg, wt + (size_t)2 * HID * G4, outp);
}